// Round 5
// baseline (432.554 us; speedup 1.0000x reference)
//
#include <hip/hip_runtime.h>
#include <float.h>

// Strategy: the harness's np reference computes BOTH z (convs) and dists in
// FLOAT32. We replicate its f32 rounding semantics bitwise:
//   conv: im2col/BLAS-style sequential fused-FMA dot over (ic,kh,kw),
//         bias added at end (one f32 add), relu.
//   dists[r,k] = fl( fl(sx_r + sc_k) - 2*dot(r,k) ),
//         dot = sequential fused-FMA d=0..63 (BLAS sgemm microkernel order).
//   argmin with first-index tie-break (np.argmin).
// sx bits are argmin-invariant (uniform per-row grid shift); sc errors ~1e-14
// are negligible; only formula shape + dot order matter. All replica math via
// __fmaf_rn/__fadd_rn/__fmul_rn so the compiler cannot contract/reassociate.
//
// Workspace (floats, ~54.5 MB):
//   out1: 8388608, out2: 4194304, flat: 1048576,
//   sx: 16384, sc: 8192, pmin: [4][16384], pidx: [4][16384]

// ---------------- conv1: x[16,3,256,256] -> relu -> out1[16,32,128,128], k4 s2 p1
__global__ __launch_bounds__(256) void conv1_kernel(const float* __restrict__ in,
                                                    const float* __restrict__ w,   // [32][3][4][4]
                                                    const float* __restrict__ bias,// [32]
                                                    float* __restrict__ out) {
    int p = blockIdx.x * 256 + threadIdx.x;        // 262144
    int ow = p & 127, oh = (p >> 7) & 127, bb = p >> 14;
    float taps[48];                                 // [ic][kh][kw]
    for (int ic = 0; ic < 3; ++ic) {
        const float* ip = in + (bb * 3 + ic) * 65536;
        #pragma unroll
        for (int kh = 0; kh < 4; ++kh) {
            int ih = oh * 2 - 1 + kh;
            #pragma unroll
            for (int kw = 0; kw < 4; ++kw) {
                int iw = ow * 2 - 1 + kw;
                bool ok = ((unsigned)ih < 256u) && ((unsigned)iw < 256u);
                taps[ic * 16 + kh * 4 + kw] = ok ? ip[ih * 256 + iw] : 0.0f;
            }
        }
    }
    float* op = out + bb * (32 * 16384) + oh * 128 + ow;
    for (int oc = 0; oc < 32; ++oc) {
        float acc = 0.0f;
        const float* wp = w + oc * 48;             // wave-uniform
        #pragma unroll
        for (int t = 0; t < 48; ++t) acc = __fmaf_rn(taps[t], wp[t], acc);
        acc = __fadd_rn(acc, bias[oc]);
        op[oc * 16384] = fmaxf(acc, 0.0f);
    }
}

// ---------------- conv2: out1 -> relu -> out2[16,64,64,64]  ((ic,kh,kw) chain)
__global__ __launch_bounds__(256) void conv2_kernel(const float* __restrict__ in,  // [16][32][128][128]
                                                    const float* __restrict__ w,   // [64][32][4][4]
                                                    const float* __restrict__ bias,// [64]
                                                    float* __restrict__ out) {
    int p = blockIdx.x * 256 + threadIdx.x;        // 65536
    int ow = p & 63, oh = (p >> 6) & 63, bb = p >> 12;
    int oc0 = blockIdx.y * 16;
    float acc[16];
    #pragma unroll
    for (int j = 0; j < 16; ++j) acc[j] = 0.0f;
    const float* ibase = in + bb * 32 * 16384;
    for (int ic = 0; ic < 32; ++ic) {
        const float* ip = ibase + ic * 16384;
        float taps[16];
        #pragma unroll
        for (int kh = 0; kh < 4; ++kh) {
            int ih = oh * 2 - 1 + kh;
            #pragma unroll
            for (int kw = 0; kw < 4; ++kw) {
                int iw = ow * 2 - 1 + kw;
                bool ok = ((unsigned)ih < 128u) && ((unsigned)iw < 128u);
                taps[kh * 4 + kw] = ok ? ip[ih * 128 + iw] : 0.0f;
            }
        }
        #pragma unroll
        for (int t = 0; t < 16; ++t) {
            float tp = taps[t];
            #pragma unroll
            for (int j = 0; j < 16; ++j)
                acc[j] = __fmaf_rn(tp, w[(oc0 + j) * 512 + ic * 16 + t], acc[j]);
        }
    }
    float* op = out + bb * (64 * 4096) + oh * 64 + ow;
    #pragma unroll
    for (int j = 0; j < 16; ++j) {
        float y = __fadd_rn(acc[j], bias[oc0 + j]);
        op[(oc0 + j) * 4096] = fmaxf(y, 0.0f);
    }
}

// ---------------- conv3: out2 -> relu -> flat[16384][64]  ((ic,kh,kw) chain)
__global__ __launch_bounds__(256) void conv3_kernel(const float* __restrict__ in,  // [16][64][64][64]
                                                    const float* __restrict__ w,   // [64][64][4][4]
                                                    const float* __restrict__ bias,// [64]
                                                    float* __restrict__ flat) {
    int p = blockIdx.x * 256 + threadIdx.x;        // 16384 (== flat row)
    int ow = p & 31, oh = (p >> 5) & 31, bb = p >> 10;
    int oc0 = blockIdx.y * 8;
    float acc[8];
    #pragma unroll
    for (int j = 0; j < 8; ++j) acc[j] = 0.0f;
    const float* ibase = in + bb * 64 * 4096;
    for (int ic = 0; ic < 64; ++ic) {
        const float* ip = ibase + ic * 4096;
        float taps[16];
        #pragma unroll
        for (int kh = 0; kh < 4; ++kh) {
            int ih = oh * 2 - 1 + kh;
            #pragma unroll
            for (int kw = 0; kw < 4; ++kw) {
                int iw = ow * 2 - 1 + kw;
                bool ok = ((unsigned)ih < 64u) && ((unsigned)iw < 64u);
                taps[kh * 4 + kw] = ok ? ip[ih * 64 + iw] : 0.0f;
            }
        }
        #pragma unroll
        for (int t = 0; t < 16; ++t) {
            float tp = taps[t];
            #pragma unroll
            for (int j = 0; j < 8; ++j)
                acc[j] = __fmaf_rn(tp, w[(oc0 + j) * 1024 + ic * 16 + t], acc[j]);
        }
    }
    float* op = flat + (size_t)p * 64 + oc0;
    #pragma unroll
    for (int j = 0; j < 8; ++j) {
        float y = __fadd_rn(acc[j], bias[oc0 + j]);
        op[j] = fmaxf(y, 0.0f);
    }
}

// ---------------- row norms: sx[16384] (flat), sc[8192] (codebook)
// numpy pairwise-8 structure (exact bits don't matter — see header — but free)
__global__ __launch_bounds__(256) void rownorm_kernel(const float* __restrict__ flat,
                                                      const float* __restrict__ cb,
                                                      float* __restrict__ sx,
                                                      float* __restrict__ sc) {
    int i = blockIdx.x * 256 + threadIdx.x;        // 24576
    const float* src;
    float* dst;
    if (i < 16384) { src = flat + (size_t)i * 64; dst = sx + i; }
    else           { src = cb + (size_t)(i - 16384) * 64; dst = sc + (i - 16384); }
    float r[8];
    #pragma unroll
    for (int j = 0; j < 8; ++j) r[j] = __fmul_rn(src[j], src[j]);
    #pragma unroll
    for (int b = 1; b < 8; ++b)
        #pragma unroll
        for (int j = 0; j < 8; ++j)
            r[j] = __fadd_rn(r[j], __fmul_rn(src[b * 8 + j], src[b * 8 + j]));
    float s01 = __fadd_rn(r[0], r[1]), s23 = __fadd_rn(r[2], r[3]);
    float s45 = __fadd_rn(r[4], r[5]), s67 = __fadd_rn(r[6], r[7]);
    *dst = __fadd_rn(__fadd_rn(s01, s23), __fadd_rn(s45, s67));
}

// ---------------- VQ pass1: argmin_k over this split of fl(fl(sx+sc) - 2*dot)
#define VQ_RT 128
#define VQ_CT 128
#define LDP   68

__global__ __launch_bounds__(256) void vq_kernel(const float* __restrict__ flat,
                                                 const float* __restrict__ cb,
                                                 const float* __restrict__ sx,
                                                 const float* __restrict__ sc,
                                                 float* __restrict__ pmin,     // [4][16384]
                                                 int* __restrict__ pidx) {     // [4][16384]
    __shared__ float xs[VQ_RT * LDP];
    __shared__ float sxs[VQ_RT];
    __shared__ float cs[VQ_CT * LDP];
    __shared__ float bs[VQ_CT];
    int tid = threadIdx.x;
    int rowbase = blockIdx.x * VQ_RT;
    int kbase = blockIdx.y * 2048;

    {
        const float4* f4 = (const float4*)(flat + (size_t)rowbase * 64);
        #pragma unroll
        for (int s = 0; s < 8; ++s) {
            int idx = tid + 256 * s;
            float4 v = f4[idx];
            int r = idx >> 4, c = idx & 15;
            *(float4*)&xs[r * LDP + c * 4] = v;
        }
        if (tid < VQ_RT) sxs[tid] = sx[rowbase + tid];
    }

    int tr = tid >> 4, tc = tid & 15;              // rows tr+16i, codes tc+16j
    float best[8];
    int bidx[8];
    #pragma unroll
    for (int i = 0; i < 8; ++i) { best[i] = FLT_MAX; bidx[i] = 0x7fffffff; }

    for (int tile = 0; tile < 16; ++tile) {
        int cb0 = kbase + tile * VQ_CT;
        __syncthreads();                           // covers xs/sxs staging + prev readers
        {
            const float4* c4 = (const float4*)(cb + (size_t)cb0 * 64);
            #pragma unroll
            for (int s = 0; s < 8; ++s) {
                int idx = tid + 256 * s;
                float4 v = c4[idx];
                int r = idx >> 4, c = idx & 15;
                *(float4*)&cs[r * LDP + c * 4] = v;
            }
            if (tid < VQ_CT) bs[tid] = sc[cb0 + tid];
        }
        __syncthreads();

        float acc[8][8];
        #pragma unroll
        for (int i = 0; i < 8; ++i)
            #pragma unroll
            for (int j = 0; j < 8; ++j) acc[i][j] = 0.0f;

        // dot: strictly sequential d=0..63 fused FMA per (row, code) — BLAS order
        for (int d = 0; d < 64; d += 4) {
            float4 ax[8], bc[8];
            #pragma unroll
            for (int i = 0; i < 8; ++i) ax[i] = *(const float4*)&xs[(tr + 16 * i) * LDP + d];
            #pragma unroll
            for (int j = 0; j < 8; ++j) bc[j] = *(const float4*)&cs[(tc + 16 * j) * LDP + d];
            #pragma unroll
            for (int i = 0; i < 8; ++i)
                #pragma unroll
                for (int j = 0; j < 8; ++j) {
                    acc[i][j] = __fmaf_rn(ax[i].x, bc[j].x, acc[i][j]);
                    acc[i][j] = __fmaf_rn(ax[i].y, bc[j].y, acc[i][j]);
                    acc[i][j] = __fmaf_rn(ax[i].z, bc[j].z, acc[i][j]);
                    acc[i][j] = __fmaf_rn(ax[i].w, bc[j].w, acc[i][j]);
                }
        }

        #pragma unroll
        for (int j = 0; j < 8; ++j) {              // ascending k per lane
            int code = cb0 + tc + 16 * j;
            float scj = bs[tc + 16 * j];
            #pragma unroll
            for (int i = 0; i < 8; ++i) {
                float t1 = __fadd_rn(sxs[tr + 16 * i], scj);   // fl(sx+sc) — ref's add
                float q = __fmaf_rn(-2.0f, acc[i][j], t1);     // == RN(t1 - 2*acc), 2*acc exact
                if (q < best[i]) { best[i] = q; bidx[i] = code; }  // strict <: first-min
            }
        }
    }

    // cross-lane merge per row (reuse cs), first-index ties
    __syncthreads();
    float* rm1 = cs;                         // [128][16]
    int* rix = (int*)(cs + 2048);            // [128][16]
    #pragma unroll
    for (int i = 0; i < 8; ++i) {
        rm1[(tr + 16 * i) * 16 + tc] = best[i];
        rix[(tr + 16 * i) * 16 + tc] = bidx[i];
    }
    __syncthreads();
    if (tid < VQ_RT) {
        float m = FLT_MAX; int mi = 0x7fffffff;
        for (int t2 = 0; t2 < 16; ++t2) {
            float v = rm1[tid * 16 + t2];
            int ix = rix[tid * 16 + t2];
            if (v < m || (v == m && ix < mi)) { m = v; mi = ix; }
        }
        int o = blockIdx.y * 16384 + rowbase + tid;
        pmin[o] = m; pidx[o] = mi;
    }
}

// ---------------- final: merge 4 k-splits (first-index ties), write float idx
__global__ __launch_bounds__(256) void vq_final_kernel(const float* __restrict__ pmin,
                                                       const int* __restrict__ pidx,
                                                       float* __restrict__ out) {
    int r = blockIdx.x * 256 + threadIdx.x;        // 16384
    float m = FLT_MAX; int mi = 0x7fffffff;
    #pragma unroll
    for (int s = 0; s < 4; ++s) {
        float v = pmin[s * 16384 + r];
        int ix = pidx[s * 16384 + r];
        if (v < m || (v == m && ix < mi)) { m = v; mi = ix; }
    }
    out[r] = (float)mi;                            // idx as float32 value
    if (r == 0) out[16384] = 0.0f;                 // second tuple output
}

extern "C" void kernel_launch(void* const* d_in, const int* in_sizes, int n_in,
                              void* d_out, int out_size, void* d_ws, size_t ws_size,
                              hipStream_t stream) {
    const float* x  = (const float*)d_in[0];
    const float* w1 = (const float*)d_in[1];
    const float* b1 = (const float*)d_in[2];
    const float* w2 = (const float*)d_in[3];
    const float* b2 = (const float*)d_in[4];
    const float* w3 = (const float*)d_in[5];
    const float* b3 = (const float*)d_in[6];
    const float* cb = (const float*)d_in[7];

    float* ws   = (float*)d_ws;
    float* out1 = ws;                        // 8388608
    float* out2 = out1 + 8388608;            // 4194304
    float* flat = out2 + 4194304;            // 1048576
    float* sx   = flat + 1048576;            // 16384
    float* sc   = sx + 16384;                // 8192
    float* pmin = sc + 8192;                 // 65536
    int*   pidx = (int*)(pmin + 65536);      // 65536
    float* out  = (float*)d_out;

    hipLaunchKernelGGL(conv1_kernel,  dim3(1024), dim3(256), 0, stream, x, w1, b1, out1);
    hipLaunchKernelGGL(conv2_kernel,  dim3(256, 4), dim3(256), 0, stream, out1, w2, b2, out2);
    hipLaunchKernelGGL(conv3_kernel,  dim3(64, 8), dim3(256), 0, stream, out2, w3, b3, flat);
    hipLaunchKernelGGL(rownorm_kernel, dim3(96), dim3(256), 0, stream, flat, cb, sx, sc);
    hipLaunchKernelGGL(vq_kernel,     dim3(128, 4), dim3(256), 0, stream, flat, cb, sx, sc, pmin, pidx);
    hipLaunchKernelGGL(vq_final_kernel, dim3(64), dim3(256), 0, stream, pmin, pidx, out);
}